// Round 8
// baseline (264.759 us; speedup 1.0000x reference)
//
#include <hip/hip_runtime.h>

#define HCH 32
#define NDIM 1024
#define SEG 512                  // pixels per wave (half row)
#define PAIRS (SEG / 64)         // 8 iterations of 64 px (2 MFMA tiles)

using half2v   = __attribute__((ext_vector_type(2))) _Float16;
using half8    = __attribute__((ext_vector_type(8))) _Float16;
using floatx16 = __attribute__((ext_vector_type(16))) float;

// One wave per half-row (b,i,seg). R6 body at FULL occupancy:
// VGPR=64 (measured R7) allows 8 waves/SIMD; launch_bounds(256,8) makes all
// 2048 blocks (8/CU, 16KB LDS each = 128KB) resident in one round.
// Stage the wave's d/wj streams into private LDS up front (4 KB in flight),
// then 8x 64-px pairs from LDS: layer1 packed f16 -> 2x2 32x32x16 MFMA ->
// relu+W3 dot -> one shfl_xor(32) -> softplus -> coalesced 256B store.
__global__ __launch_bounds__(256, 8)
void lf_kernel(const float* __restrict__ weights,
               const float* __restrict__ distances,
               const float* __restrict__ W1,
               const float* __restrict__ b1,
               const float* __restrict__ W2,
               const float* __restrict__ b2,
               const float* __restrict__ W3,
               const float* __restrict__ b3,
               float* __restrict__ out)
{
    __shared__ float sd[4][SEG];   // per-wave private d chunk (2 KB/wave)
    __shared__ float sw[4][SEG];   // per-wave private wj chunk

    const int lane = threadIdx.x & 63;
    const int wv = threadIdx.x >> 6;
    const int wave_gid = __builtin_amdgcn_readfirstlane(blockIdx.x * 4 + wv);
    const int row_id = wave_gid >> 1;          // (b,i) row
    const int j_begin = (wave_gid & 1) * SEG;  // half within the row
    const int b = row_id >> 10;                // N = 1024

    const int col = lane & 31;                 // pixel-in-tile (B n-index, D col)
    const int half_id = lane >> 5;
    const bool hi = (half_id != 0);
    const int kb = half_id * 8;                // k-block base for A/B frags

    const float* __restrict__ drow = distances + (size_t)row_id * NDIM + j_begin;
    const float* __restrict__ wrow = weights + b * NDIM + j_begin;
    float* __restrict__ orow = out + (size_t)row_id * NDIM + j_begin;

    // ---- Issue the bulk stream loads FIRST (16 B/lane x4 = 4 KB in flight) ----
    const float4 dv0 = *(const float4*)(drow + 4 * lane);
    const float4 dv1 = *(const float4*)(drow + 256 + 4 * lane);
    const float4 wv0 = *(const float4*)(wrow + 4 * lane);
    const float4 wv1 = *(const float4*)(wrow + 256 + 4 * lane);

    // ---- Weight prologue (overlaps the stream loads) ----
    const float wi = weights[row_id];

    // Layer-1 constants as f16 pairs. Pair p<4 -> channels kb+2p,+1 (frag0);
    // p>=4 -> 16+kb+2(p-4)+{0,1} (frag1). base = W1[0,ch]*wi + b1[ch] (f32 fold).
    half2v base2[8], cc2[8], ee2[8];
#pragma unroll
    for (int p = 0; p < 8; ++p) {
        const int chA = (p < 4) ? (kb + 2 * p) : (16 + kb + 2 * (p - 4));
        const int chB = chA + 1;
        base2[p] = half2v{(_Float16)fmaf(W1[chA], wi, b1[chA]),
                          (_Float16)fmaf(W1[chB], wi, b1[chB])};
        cc2[p] = half2v{(_Float16)W1[HCH + chA], (_Float16)W1[HCH + chB]};
        ee2[p] = half2v{(_Float16)W1[2 * HCH + chA], (_Float16)W1[2 * HCH + chB]};
    }

    // A fragments: A[m=c][k=h] = W2[h][c]; c = col, h = kb+j / 16+kb+j.
    half8 a0, a1;
#pragma unroll
    for (int j = 0; j < 8; ++j) {
        a0[j] = (_Float16)W2[(kb + j) * HCH + col];
        a1[j] = (_Float16)W2[(16 + kb + j) * HCH + col];
    }

    // C-init = b2 broadcast along cols; W3 gathered per accumulator register.
    // D row for reg r: (r&3) + 8*(r>>2) + 4*half_id  [measured C/D layout, 32x32]
    floatx16 cinit;
    float w3r[16];
#pragma unroll
    for (int r = 0; r < 16; ++r) {
        const int rc = (r & 3) + 8 * (r >> 2) + 4 * half_id;
        cinit[r] = b2[rc];
        w3r[r]   = W3[rc];
    }
    const float b3v = b3[0];

    // ---- Park the streams in LDS (vmcnt waits happen here) ----
    *(float4*)&sd[wv][4 * lane]       = dv0;
    *(float4*)&sd[wv][256 + 4 * lane] = dv1;
    *(float4*)&sw[wv][4 * lane]       = wv0;
    *(float4*)&sw[wv][256 + 4 * lane] = wv1;
    __syncthreads();

    const half2v zero2 = half2v{(_Float16)0.0f, (_Float16)0.0f};

#pragma unroll
    for (int p = 0; p < PAIRS; ++p) {
        // Stream values from LDS: lanes 0..31 / 32..63 read identical
        // addresses (broadcast, conflict-free).
        const float dA = sd[wv][p * 64 + col];
        const float dB = sd[wv][p * 64 + 32 + col];
        const float wA = sw[wv][p * 64 + col];
        const float wB = sw[wv][p * 64 + 32 + col];

        // ---- Layer 1 (packed f16), two independent tiles ----
        const _Float16 dhA = (_Float16)dA, wjhA = (_Float16)wA;
        const _Float16 dhB = (_Float16)dB, wjhB = (_Float16)wB;
        const half2v d2A = half2v{dhA, dhA}, wj2A = half2v{wjhA, wjhA};
        const half2v d2B = half2v{dhB, dhB}, wj2B = half2v{wjhB, wjhB};

        union Frag { half8 v; half2v h[4]; } f0A, f1A, f0B, f1B;
#pragma unroll
        for (int q = 0; q < 4; ++q) {
            half2v tA0 = __builtin_elementwise_fma(cc2[q], wj2A, base2[q]);
            tA0 = __builtin_elementwise_fma(ee2[q], d2A, tA0);
            f0A.h[q] = __builtin_elementwise_max(tA0, zero2);
            half2v tA1 = __builtin_elementwise_fma(cc2[q + 4], wj2A, base2[q + 4]);
            tA1 = __builtin_elementwise_fma(ee2[q + 4], d2A, tA1);
            f1A.h[q] = __builtin_elementwise_max(tA1, zero2);
            half2v tB0 = __builtin_elementwise_fma(cc2[q], wj2B, base2[q]);
            tB0 = __builtin_elementwise_fma(ee2[q], d2B, tB0);
            f0B.h[q] = __builtin_elementwise_max(tB0, zero2);
            half2v tB1 = __builtin_elementwise_fma(cc2[q + 4], wj2B, base2[q + 4]);
            tB1 = __builtin_elementwise_fma(ee2[q + 4], d2B, tB1);
            f1B.h[q] = __builtin_elementwise_max(tB1, zero2);
        }

        // ---- Layer 2: two independent MFMA chains ----
        floatx16 accA = __builtin_amdgcn_mfma_f32_32x32x16_f16(a0, f0A.v, cinit, 0, 0, 0);
        floatx16 accB = __builtin_amdgcn_mfma_f32_32x32x16_f16(a0, f0B.v, cinit, 0, 0, 0);
        accA = __builtin_amdgcn_mfma_f32_32x32x16_f16(a1, f1A.v, accA, 0, 0, 0);
        accB = __builtin_amdgcn_mfma_f32_32x32x16_f16(a1, f1B.v, accB, 0, 0, 0);

        // ---- Layer 3: relu + W3 dot, two tiles interleaved ----
        float sA0 = 0.0f, sA1 = 0.0f, sB0 = 0.0f, sB1 = 0.0f;
#pragma unroll
        for (int r = 0; r < 16; r += 2) {
            sA0 = fmaf(fmaxf(accA[r + 0], 0.0f), w3r[r + 0], sA0);
            sA1 = fmaf(fmaxf(accA[r + 1], 0.0f), w3r[r + 1], sA1);
            sB0 = fmaf(fmaxf(accB[r + 0], 0.0f), w3r[r + 0], sB0);
            sB1 = fmaf(fmaxf(accB[r + 1], 0.0f), w3r[r + 1], sB1);
        }
        const float sA = sA0 + sA1;
        const float sB = sB0 + sB1;

        // One shuffle resolves both tiles: send the tile the other half needs.
        const float u = hi ? sA : sB;
        const float other = __shfl_xor(u, 32, 64);
        const float loc = hi ? sB : sA;
        const float full = loc + other;  // lane<32: tileA col; lane>=32: tileB col

        // softplus(x) = max(x,0) + log(1 + exp(-|x|)), 64 distinct pixels
        const float x = full + b3v;
        const float sp = fmaxf(x, 0.0f) + __logf(1.0f + __expf(-fabsf(x)));

        orow[p * 64 + lane] = sp;  // coalesced 256B, all 64 lanes
    }
}

extern "C" void kernel_launch(void* const* d_in, const int* in_sizes, int n_in,
                              void* d_out, int out_size, void* d_ws, size_t ws_size,
                              hipStream_t stream) {
    const float* weights   = (const float*)d_in[0];
    const float* distances = (const float*)d_in[1];
    const float* W1 = (const float*)d_in[2];
    const float* b1 = (const float*)d_in[3];
    const float* W2 = (const float*)d_in[4];
    const float* b2 = (const float*)d_in[5];
    const float* W3 = (const float*)d_in[6];
    const float* b3 = (const float*)d_in[7];
    float* out = (float*)d_out;

    const int rows_total = 4 * 1024;            // B * N
    dim3 grid(rows_total * (NDIM / SEG) / 4);   // 2048 blocks, 4 waves each
    lf_kernel<<<grid, 256, 0, stream>>>(weights, distances, W1, b1, W2, b2, W3, b3, out);
}

// Round 9
// 101.605 us; speedup vs baseline: 2.6058x; 2.6058x over previous
//
#include <hip/hip_runtime.h>

#define HCH 32
#define NDIM 1024
#define SEG 512                  // pixels per wave (half row)
#define PAIRS (SEG / 64)         // 8 iterations of 64 px (2 MFMA tiles)

using half2v   = __attribute__((ext_vector_type(2))) _Float16;
using hh2      = __attribute__((ext_vector_type(2))) __fp16;
using half8    = __attribute__((ext_vector_type(8))) _Float16;
using floatx16 = __attribute__((ext_vector_type(16))) float;

// One wave per half-row (b,i,seg), 4 waves/SIMD (reg ceiling, measured R8).
// d/wj streams staged into wave-PRIVATE LDS as pre-splatted f16 pairs
// ({v,v} per dword) -> inner loop reads MFMA-ready splats, no per-pair cvt.
// No __syncthreads needed (in-wave lgkm ordering). Per 64-px pair:
// layer1 packed f16 -> 2x2 v_mfma_f32_32x32x16_f16 (two independent tiles)
// -> f32 relu+W3 dot -> one shfl_xor(32) resolves both tiles -> softplus
// -> one coalesced 256B store.
__global__ __launch_bounds__(256, 4)
void lf_kernel(const float* __restrict__ weights,
               const float* __restrict__ distances,
               const float* __restrict__ W1,
               const float* __restrict__ b1,
               const float* __restrict__ W2,
               const float* __restrict__ b2,
               const float* __restrict__ W3,
               const float* __restrict__ b3,
               float* __restrict__ out)
{
    __shared__ unsigned int sd[4][SEG];   // splatted f16 {v,v} per px, 2KB/wave
    __shared__ unsigned int sw[4][SEG];

    const int lane = threadIdx.x & 63;
    const int wv = threadIdx.x >> 6;
    const int wave_gid = __builtin_amdgcn_readfirstlane(blockIdx.x * 4 + wv);
    const int row_id = wave_gid >> 1;          // (b,i) row
    const int j_begin = (wave_gid & 1) * SEG;  // half within the row
    const int b = row_id >> 10;                // N = 1024

    const int col = lane & 31;                 // pixel-in-tile (B n-index, D col)
    const int half_id = lane >> 5;
    const bool hi = (half_id != 0);
    const int kb = half_id * 8;                // k-block base for A/B frags

    const float* __restrict__ drow = distances + (size_t)row_id * NDIM + j_begin;
    const float* __restrict__ wrow = weights + b * NDIM + j_begin;
    float* __restrict__ orow = out + (size_t)row_id * NDIM + j_begin;

    // ---- Issue the bulk stream loads FIRST (16 B/lane x4 in flight) ----
    const float4 dv0 = *(const float4*)(drow + 4 * lane);
    const float4 dv1 = *(const float4*)(drow + 256 + 4 * lane);
    const float4 wv0 = *(const float4*)(wrow + 4 * lane);
    const float4 wv1 = *(const float4*)(wrow + 256 + 4 * lane);

    // ---- Weight prologue (overlaps the stream loads) ----
    const float wi = weights[row_id];

    // Layer-1 constants as f16 pairs. Pair p<4 -> channels kb+2p,+1 (frag0);
    // p>=4 -> 16+kb+2(p-4)+{0,1} (frag1). base = W1[0,ch]*wi + b1[ch] (f32 fold).
    half2v base2[8], cc2[8], ee2[8];
#pragma unroll
    for (int p = 0; p < 8; ++p) {
        const int chA = (p < 4) ? (kb + 2 * p) : (16 + kb + 2 * (p - 4));
        const int chB = chA + 1;
        base2[p] = half2v{(_Float16)fmaf(W1[chA], wi, b1[chA]),
                          (_Float16)fmaf(W1[chB], wi, b1[chB])};
        cc2[p] = half2v{(_Float16)W1[HCH + chA], (_Float16)W1[HCH + chB]};
        ee2[p] = half2v{(_Float16)W1[2 * HCH + chA], (_Float16)W1[2 * HCH + chB]};
    }

    // A fragments: A[m=c][k=h] = W2[h][c]; c = col, h = kb+j / 16+kb+j.
    half8 a0, a1;
#pragma unroll
    for (int j = 0; j < 8; ++j) {
        a0[j] = (_Float16)W2[(kb + j) * HCH + col];
        a1[j] = (_Float16)W2[(16 + kb + j) * HCH + col];
    }

    // C-init = b2 broadcast along cols; W3 gathered per accumulator register.
    // D row for reg r: (r&3) + 8*(r>>2) + 4*half_id  [measured C/D layout, 32x32]
    floatx16 cinit;
    float w3r[16];
#pragma unroll
    for (int r = 0; r < 16; ++r) {
        const int rc = (r & 3) + 8 * (r >> 2) + 4 * half_id;
        cinit[r] = b2[rc];
        w3r[r]   = W3[rc];
    }
    const float b3h = 0.5f * b3[0];   // folded into each half's dot init

    // ---- Park the streams in LDS as pre-splatted f16 pairs ----
    {
        uint4 pk;
        pk.x = __builtin_bit_cast(unsigned int, __builtin_amdgcn_cvt_pkrtz(dv0.x, dv0.x));
        pk.y = __builtin_bit_cast(unsigned int, __builtin_amdgcn_cvt_pkrtz(dv0.y, dv0.y));
        pk.z = __builtin_bit_cast(unsigned int, __builtin_amdgcn_cvt_pkrtz(dv0.z, dv0.z));
        pk.w = __builtin_bit_cast(unsigned int, __builtin_amdgcn_cvt_pkrtz(dv0.w, dv0.w));
        *(uint4*)&sd[wv][4 * lane] = pk;
        pk.x = __builtin_bit_cast(unsigned int, __builtin_amdgcn_cvt_pkrtz(dv1.x, dv1.x));
        pk.y = __builtin_bit_cast(unsigned int, __builtin_amdgcn_cvt_pkrtz(dv1.y, dv1.y));
        pk.z = __builtin_bit_cast(unsigned int, __builtin_amdgcn_cvt_pkrtz(dv1.z, dv1.z));
        pk.w = __builtin_bit_cast(unsigned int, __builtin_amdgcn_cvt_pkrtz(dv1.w, dv1.w));
        *(uint4*)&sd[wv][256 + 4 * lane] = pk;
        pk.x = __builtin_bit_cast(unsigned int, __builtin_amdgcn_cvt_pkrtz(wv0.x, wv0.x));
        pk.y = __builtin_bit_cast(unsigned int, __builtin_amdgcn_cvt_pkrtz(wv0.y, wv0.y));
        pk.z = __builtin_bit_cast(unsigned int, __builtin_amdgcn_cvt_pkrtz(wv0.z, wv0.z));
        pk.w = __builtin_bit_cast(unsigned int, __builtin_amdgcn_cvt_pkrtz(wv0.w, wv0.w));
        *(uint4*)&sw[wv][4 * lane] = pk;
        pk.x = __builtin_bit_cast(unsigned int, __builtin_amdgcn_cvt_pkrtz(wv1.x, wv1.x));
        pk.y = __builtin_bit_cast(unsigned int, __builtin_amdgcn_cvt_pkrtz(wv1.y, wv1.y));
        pk.z = __builtin_bit_cast(unsigned int, __builtin_amdgcn_cvt_pkrtz(wv1.z, wv1.z));
        pk.w = __builtin_bit_cast(unsigned int, __builtin_amdgcn_cvt_pkrtz(wv1.w, wv1.w));
        *(uint4*)&sw[wv][256 + 4 * lane] = pk;
    }
    // No __syncthreads: LDS regions are wave-private; in-wave lgkm ordering
    // guarantees the reads below see the writes above.

    const half2v zero2 = half2v{(_Float16)0.0f, (_Float16)0.0f};

    // Rolled depth-1 prefetch of the next pair's stream dwords.
    unsigned int uA = sd[wv][col],      uB = sd[wv][32 + col];
    unsigned int vA = sw[wv][col],      vB = sw[wv][32 + col];

#pragma unroll
    for (int p = 0; p < PAIRS; ++p) {
        const int pn = (p + 1 < PAIRS) ? (p + 1) : 0;
        const unsigned int nuA = sd[wv][pn * 64 + col];
        const unsigned int nuB = sd[wv][pn * 64 + 32 + col];
        const unsigned int nvA = sw[wv][pn * 64 + col];
        const unsigned int nvB = sw[wv][pn * 64 + 32 + col];

        const half2v d2A = __builtin_bit_cast(half2v, uA);
        const half2v d2B = __builtin_bit_cast(half2v, uB);
        const half2v wj2A = __builtin_bit_cast(half2v, vA);
        const half2v wj2B = __builtin_bit_cast(half2v, vB);

        // ---- Layer 1 (packed f16), two independent tiles ----
        union Frag { half8 v; half2v h[4]; } f0A, f1A, f0B, f1B;
#pragma unroll
        for (int q = 0; q < 4; ++q) {
            half2v tA0 = __builtin_elementwise_fma(cc2[q], wj2A, base2[q]);
            tA0 = __builtin_elementwise_fma(ee2[q], d2A, tA0);
            f0A.h[q] = __builtin_elementwise_max(tA0, zero2);
            half2v tA1 = __builtin_elementwise_fma(cc2[q + 4], wj2A, base2[q + 4]);
            tA1 = __builtin_elementwise_fma(ee2[q + 4], d2A, tA1);
            f1A.h[q] = __builtin_elementwise_max(tA1, zero2);
            half2v tB0 = __builtin_elementwise_fma(cc2[q], wj2B, base2[q]);
            tB0 = __builtin_elementwise_fma(ee2[q], d2B, tB0);
            f0B.h[q] = __builtin_elementwise_max(tB0, zero2);
            half2v tB1 = __builtin_elementwise_fma(cc2[q + 4], wj2B, base2[q + 4]);
            tB1 = __builtin_elementwise_fma(ee2[q + 4], d2B, tB1);
            f1B.h[q] = __builtin_elementwise_max(tB1, zero2);
        }

        // ---- Layer 2: two independent MFMA chains ----
        floatx16 accA = __builtin_amdgcn_mfma_f32_32x32x16_f16(a0, f0A.v, cinit, 0, 0, 0);
        floatx16 accB = __builtin_amdgcn_mfma_f32_32x32x16_f16(a0, f0B.v, cinit, 0, 0, 0);
        accA = __builtin_amdgcn_mfma_f32_32x32x16_f16(a1, f1A.v, accA, 0, 0, 0);
        accB = __builtin_amdgcn_mfma_f32_32x32x16_f16(a1, f1B.v, accB, 0, 0, 0);

        // ---- Layer 3: relu + W3 dot, two tiles interleaved (b3/2 folded) ----
        float sA0 = b3h, sA1 = 0.0f, sB0 = b3h, sB1 = 0.0f;
#pragma unroll
        for (int r = 0; r < 16; r += 2) {
            sA0 = fmaf(fmaxf(accA[r + 0], 0.0f), w3r[r + 0], sA0);
            sA1 = fmaf(fmaxf(accA[r + 1], 0.0f), w3r[r + 1], sA1);
            sB0 = fmaf(fmaxf(accB[r + 0], 0.0f), w3r[r + 0], sB0);
            sB1 = fmaf(fmaxf(accB[r + 1], 0.0f), w3r[r + 1], sB1);
        }
        const float sA = sA0 + sA1;
        const float sB = sB0 + sB1;

        // One shuffle resolves both tiles: send the tile the other half needs.
        const float u = hi ? sA : sB;
        const float other = __shfl_xor(u, 32, 64);
        const float loc = hi ? sB : sA;
        const float x = loc + other;   // includes b3 (b3/2 from each half)

        // softplus(x) = max(x,0) + log(1 + exp(-|x|)), 64 distinct pixels
        const float sp = fmaxf(x, 0.0f) + __logf(1.0f + __expf(-fabsf(x)));

        orow[p * 64 + lane] = sp;  // coalesced 256B, all 64 lanes

        uA = nuA; uB = nuB; vA = nvA; vB = nvB;
    }
}

extern "C" void kernel_launch(void* const* d_in, const int* in_sizes, int n_in,
                              void* d_out, int out_size, void* d_ws, size_t ws_size,
                              hipStream_t stream) {
    const float* weights   = (const float*)d_in[0];
    const float* distances = (const float*)d_in[1];
    const float* W1 = (const float*)d_in[2];
    const float* b1 = (const float*)d_in[3];
    const float* W2 = (const float*)d_in[4];
    const float* b2 = (const float*)d_in[5];
    const float* W3 = (const float*)d_in[6];
    const float* b3 = (const float*)d_in[7];
    float* out = (float*)d_out;

    const int rows_total = 4 * 1024;            // B * N
    dim3 grid(rows_total * (NDIM / SEG) / 4);   // 2048 blocks, 4 waves each
    lf_kernel<<<grid, 256, 0, stream>>>(weights, distances, W1, b1, W2, b2, W3, b3, out);
}